// Round 7
// baseline (110.952 us; speedup 1.0000x reference)
//
#include <hip/hip_runtime.h>
#include <hip/hip_bf16.h>

#define N1 4096
#define N2 768
#define NCC 384      // complex (paired real) columns
#define CG 64        // complex columns per p1b block
#define WS_NEEDED 100663296ull   // 8*64*64*384 complex * 8 B

__device__ __forceinline__ float2 cadd(float2 a, float2 b){ return make_float2(a.x+b.x, a.y+b.y); }
__device__ __forceinline__ float2 csub(float2 a, float2 b){ return make_float2(a.x-b.x, a.y-b.y); }
__device__ __forceinline__ float2 cmul(float2 a, float2 b){ return make_float2(a.x*b.x - a.y*b.y, a.x*b.y + a.y*b.x); }
__device__ __forceinline__ float2 cnegi(float2 a){ return make_float2(a.y, -a.x); }  // -i * a

__device__ __forceinline__ int rev6(int p) {
  int k = 0;
  #pragma unroll
  for (int i = 0; i < 6; ++i) { k = (k << 2) | (p & 3); p >>= 2; }
  return k;
}

// In-register DIF FFT-8, natural-order outputs. X[k] = sum_j z[j] W8^{jk}.
__device__ __forceinline__ void fft8(float2 z[8]) {
  const float RH = 0.70710678118654752f;
  float2 u0=cadd(z[0],z[4]), v0=csub(z[0],z[4]);
  float2 u1=cadd(z[1],z[5]), v1=csub(z[1],z[5]);
  float2 u2=cadd(z[2],z[6]), v2=csub(z[2],z[6]);
  float2 u3=cadd(z[3],z[7]), v3=csub(z[3],z[7]);
  v1 = make_float2(RH*(v1.x+v1.y), RH*(v1.y-v1.x));
  v2 = cnegi(v2);
  v3 = make_float2(RH*(v3.y-v3.x), -RH*(v3.x+v3.y));
  float2 a0=cadd(u0,u2), b0=csub(u0,u2);
  float2 a1=cadd(u1,u3), b1=cnegi(csub(u1,u3));
  float2 c0=cadd(v0,v2), d0=csub(v0,v2);
  float2 c1=cadd(v1,v3), d1=cnegi(csub(v1,v3));
  z[0]=cadd(a0,a1); z[4]=csub(a0,a1);
  z[2]=cadd(b0,b1); z[6]=csub(b0,b1);
  z[1]=cadd(c0,c1); z[5]=csub(c0,c1);
  z[3]=cadd(d0,d1); z[7]=csub(d0,d1);
}

// P1a: FFT-64 over b (rows a+64b), * W4096^{a*kb}, for 128 complex columns
// per block. 1 KB-contiguous float4 loads staged via LDS; reg FFT-8 x
// LDS transpose x reg FFT-8. 1024 thr, 65 KB LDS, 2 blocks/CU.
__global__ __launch_bounds__(1024) void p1a_kernel(const float* __restrict__ x,
                                                   float2* __restrict__ ws) {
  __shared__ float4 S4[64*65];                   // row stride 65 f4 (130 float2)
  float2* S = reinterpret_cast<float2*>(S4);
  int bid = blockIdx.x;                          // 1536 = 8 * 192
  int b8  = bid & 7;
  int rem = bid >> 3;                            // 0..191
  int cg  = rem / 64;                            // 0..2 (128 complex cols each)
  int a   = rem % 64;
  const int t = threadIdx.x, l = t & 63, w = t >> 6;   // 16 waves

  // phase 1: rows r=4w+j; one 1024 B contiguous segment per wave instr
  const float* src = x + (size_t)b8 * N1 * N2 + (size_t)cg * 256;
  #pragma unroll
  for (int j = 0; j < 4; ++j) {
    int r   = 4*w + j;
    int row = a + 64*r;
    float4 v = *reinterpret_cast<const float4*>(src + (size_t)row * N2 + 4*l);
    S4[r*65 + l] = v;
  }
  __syncthreads();

  // phase 2: gather column c over b = 8*b1 + b0; reg FFT-8 over b1
  const int c = t & 127, b0 = t >> 7;
  float2 z[8];
  #pragma unroll
  for (int b1 = 0; b1 < 8; ++b1) z[b1] = S[(8*b1 + b0)*130 + c];
  fft8(z);                                       // z[j] = A_{b0}[j]
  {                                              // twiddle W64^{b0*j} via recurrence
    float sn, cs; __sincosf(-6.283185307179586f/64.f * (float)b0, &sn, &cs);
    float2 wstep = make_float2(cs, sn), wcur = wstep;
    #pragma unroll
    for (int j = 1; j < 8; ++j) { z[j] = cmul(z[j], wcur); wcur = cmul(wcur, wstep); }
  }
  __syncthreads();                               // all gathers done before overwrite
  #pragma unroll
  for (int j = 0; j < 8; ++j) S[(j*8 + b0)*130 + c] = z[j];
  __syncthreads();

  // phase 3: FFT-8 over b0 (fixed j), final twiddle, scatter to ws
  const int jj = t >> 7;
  #pragma unroll
  for (int b0i = 0; b0i < 8; ++b0i) z[b0i] = S[(jj*8 + b0i)*130 + c];
  fft8(z);                                       // z[m] = Y[8m + jj]
  float2 wc, w8;
  { float sn, cs; __sincosf(-6.283185307179586f/4096.f * (float)(a*jj), &sn, &cs); wc = make_float2(cs, sn); }
  { float sn, cs; __sincosf(-6.283185307179586f/4096.f * (float)(8*a),  &sn, &cs); w8 = make_float2(cs, sn); }
  float2* wdst = ws + ((size_t)b8*64)*64*NCC + (size_t)a*NCC + cg*128 + c;
  #pragma unroll
  for (int m = 0; m < 8; ++m) {
    int kb = 8*m + jj;
    wdst[(size_t)kb * 64 * NCC] = cmul(z[m], wc);
    wc = cmul(wc, w8);
  }
}

// P1b: FFT-64 over a for kb-pair {kb, 64-kb}; Hermitian unpack to packed out.
// 8-in-reg x LDS-transpose x 8-in-reg; 1024 thr, 64 KB LDS, 3 barriers.
__global__ __launch_bounds__(1024) void p1b_kernel(const float2* __restrict__ ws,
                                                   float* __restrict__ out) {
  __shared__ float2 T[2][4096];
  int bid = blockIdx.x;                          // 1536 = 8*192
  int b8  = bid & 7;
  int rem = bid >> 3;
  int cg  = rem / 32, kbt = rem % 32;
  int kb0 = (kbt == 0) ? 0  : kbt;
  int kb1 = (kbt == 0) ? 32 : 64 - kbt;
  const int t = threadIdx.x, l = t & 63, wv = (t >> 6) & 7, ti = t >> 9;
  const int kb = ti ? kb1 : kb0;

  const float2* wsrc = ws + (((size_t)b8*64 + kb)*64)*NCC + cg*CG + l;
  float2 z[8];
  #pragma unroll
  for (int a1 = 0; a1 < 8; ++a1)
    z[a1] = wsrc[(size_t)(8*a1 + wv) * NCC];
  fft8(z);                                       // z[q]=Y_{a0=wv}[q]
  float fac = -6.283185307179586f/64.0f * (float)wv;
  #pragma unroll
  for (int q = 1; q < 8; ++q) {
    float sn, cs; __sincosf(fac * (float)q, &sn, &cs);
    z[q] = cmul(z[q], make_float2(cs, sn));
  }
  #pragma unroll
  for (int q = 0; q < 8; ++q) T[ti][(q*8 + wv)*64 + l] = z[q];
  __syncthreads();
  #pragma unroll
  for (int a0 = 0; a0 < 8; ++a0) z[a0] = T[ti][(wv*8 + a0)*64 + l];
  fft8(z);                                       // z[ka1] = Z_kb[8ka1 + wv]
  __syncthreads();
  #pragma unroll
  for (int ka1 = 0; ka1 < 8; ++ka1) T[ti][(8*ka1 + wv)*64 + l] = z[ka1];  // natural ka
  __syncthreads();

  const size_t obase = (size_t)b8 * N1 * N2;
  #pragma unroll
  for (int it = 0; it < 8; ++it) {
    int ka = 8*it + wv;
    int tj, kap;
    if (kbt == 0) { tj = ti; kap = ti ? (63 - ka) : ((64 - ka) & 63); }
    else          { tj = 1 - ti; kap = 63 - ka; }
    float2 Zk = T[ti][ka*64 + l];
    float2 Zp = T[tj][kap*64 + l];
    int r = kb + 64*ka;
    float2 o;
    if (r <= 2048) o = make_float2(0.5f*(Zk.x + Zp.x), 0.5f*(Zk.y + Zp.y));
    else           o = make_float2(0.5f*(Zp.y - Zk.y), 0.5f*(Zk.x - Zp.x));
    *reinterpret_cast<float2*>(out + obase + (size_t)r * N2 + 2*(cg*CG + l)) = o;
  }
}

// ---------------- fallback path (no workspace): R3 fused pass 1 ----------------
#define PADI(i) ((i) + ((i) >> 4))
#define CPBUF 4352

__device__ __forceinline__ void bfly4p(float2* arr, int base, int M, float fac, int np) {
  float2 a0 = arr[PADI(base)], a1 = arr[PADI(base+M)];
  float2 a2 = arr[PADI(base+2*M)], a3 = arr[PADI(base+3*M)];
  float2 t0 = cadd(a0,a2), t1 = csub(a0,a2);
  float2 t2 = cadd(a1,a3), t3 = cnegi(csub(a1,a3));
  float2 y0 = cadd(t0,t2), y1 = cadd(t1,t3), y2 = csub(t0,t2), y3 = csub(t1,t3);
  float ang = fac * (float)np;
  float sn, cs; __sincosf(ang, &sn, &cs);
  float2 w1 = make_float2(cs, sn);
  float2 w2 = cmul(w1,w1);
  float2 w3 = cmul(w2,w1);
  arr[PADI(base)]     = y0;
  arr[PADI(base+M)]   = cmul(y1,w1);
  arr[PADI(base+2*M)] = cmul(y2,w2);
  arr[PADI(base+3*M)] = cmul(y3,w3);
}

__global__ __launch_bounds__(1024) void fft_seq_fused(const float* __restrict__ x,
                                                      float* __restrict__ out) {
  extern __shared__ float2 lds[];
  int bid = blockIdx.x;
  int wg  = (bid & 7) * 96 + (bid >> 3);
  int b   = wg / 96;
  int g   = wg % 96;
  const int t = threadIdx.x;
  const size_t base = (size_t)b * N1 * N2 + 8 * (size_t)g;

  for (int r = t; r < N1; r += 1024) {
    const float* p = x + base + (size_t)r * N2;
    float4 A  = *reinterpret_cast<const float4*>(p);
    float4 Bv = *reinterpret_cast<const float4*>(p + 4);
    int ip = PADI(r);
    lds[ip]             = make_float2(A.x, A.y);
    lds[CPBUF + ip]     = make_float2(A.z, A.w);
    lds[2*CPBUF + ip]   = make_float2(Bv.x, Bv.y);
    lds[3*CPBUF + ip]   = make_float2(Bv.z, Bv.w);
  }
  __syncthreads();

  const int wv  = t >> 6;
  const int cp  = wv & 3;
  const int idx = ((wv >> 2) << 6) + (t & 63);
  float2* buf = lds + cp * CPBUF;

  #pragma unroll
  for (int s = 0; s < 6; ++s) {
    int lm = 10 - 2*s;
    int M  = 1 << lm;
    float fac = -6.283185307179586f / (float)(4*M);
    #pragma unroll
    for (int jj = 0; jj < 4; ++jj) {
      int j   = idx + (jj << 8);
      int np  = j & (M-1);
      int grp = j >> lm;
      int bse = (grp << (lm+2)) + np;
      bfly4p(buf, bse, M, fac, np);
    }
    __syncthreads();
  }

  float* orow = out + base;
  #pragma unroll
  for (int i = 0; i < 4; ++i) {
    int k  = ((t & 63) << 6) + (t >> 6) + (i << 4);
    int km = (N1 - k) & (N1 - 1);
    int pk = PADI(rev6(k));
    int pn = PADI(rev6(km));
    float o[8];
    #pragma unroll
    for (int c = 0; c < 4; ++c) {
      float2 zk = lds[c*CPBUF + pk];
      float2 zn = lds[c*CPBUF + pn];
      if (k <= 2048) { o[2*c] = 0.5f*(zk.x + zn.x); o[2*c+1] = 0.5f*(zk.y + zn.y); }
      else           { o[2*c] = 0.5f*(zn.y - zk.y); o[2*c+1] = 0.5f*(zk.x - zn.x); }
    }
    float* q = orow + (size_t)k * N2;
    *reinterpret_cast<float4*>(q)     = make_float4(o[0], o[1], o[2], o[3]);
    *reinterpret_cast<float4*>(q + 4) = make_float4(o[4], o[5], o[6], o[7]);
  }
}

// Pass 2: 768-pt FFT along hidden axis, one WAVE per conjugate row pair.
// 768 = 64(lanes) x 12(registers); shfl-based cross-lane FFT-64.
__global__ __launch_bounds__(256) void fft_hid_kernel(float* __restrict__ out) {
  __shared__ float T[4][12*69];
  const int grp = threadIdx.x >> 6;
  const int l   = threadIdx.x & 63;
  int task = blockIdx.x * 4 + grp;              // 16392 = 4098*4 exact
  int b  = task / 2049;
  int t1 = task - b * 2049;                     // 0..2048
  const bool special = (t1 == 0) || (t1 == 2048);
  float* baseB = out + (size_t)b * N1 * N2;
  float* pre = baseB + (size_t)t1 * N2;
  float* pim = baseB + (size_t)(N1 - t1) * N2;

  float2 z[12];
  #pragma unroll
  for (int m = 0; m < 12; ++m) {
    float re = pre[(m << 6) + l];
    float im = special ? 0.0f : pim[(m << 6) + l];
    z[m] = make_float2(re, im);
  }

  float2 A[3][4];
  #pragma unroll
  for (int q = 0; q < 3; ++q) {
    float2 s0 = z[q], s1 = z[3+q], s2 = z[6+q], s3 = z[9+q];
    float2 t0 = cadd(s0,s2), t1v = csub(s0,s2);
    float2 t2 = cadd(s1,s3), t3 = cnegi(csub(s1,s3));
    A[q][0] = cadd(t0,t2); A[q][1] = cadd(t1v,t3);
    A[q][2] = csub(t0,t2); A[q][3] = csub(t1v,t3);
  }
  const float h3 = 0.8660254037844386f;
  const float2 W1[4] = { {1.f,0.f}, {h3,-0.5f}, {0.5f,-h3}, {0.f,-1.f} };
  const float2 W2[4] = { {1.f,0.f}, {0.5f,-h3}, {-0.5f,-h3}, {-1.f,0.f} };
  float2 y[12];
  #pragma unroll
  for (int k4 = 0; k4 < 4; ++k4) {
    float2 C0 = A[0][k4];
    float2 C1 = cmul(A[1][k4], W1[k4]);
    float2 C2 = cmul(A[2][k4], W2[k4]);
    float2 tt = cadd(C1,C2), d = csub(C1,C2);
    float2 u  = make_float2(C0.x - 0.5f*tt.x, C0.y - 0.5f*tt.y);
    float2 idd = make_float2(h3*d.y, -h3*d.x);
    y[k4]   = cadd(C0, tt);
    y[k4+4] = cadd(u, idd);
    y[k4+8] = csub(u, idd);
  }

  float base = -6.283185307179586f * (float)l / 768.0f;
  #pragma unroll
  for (int km = 1; km < 12; ++km) {
    float sn, cs; __sincosf(base * (float)km, &sn, &cs);
    y[km] = cmul(y[km], make_float2(cs, sn));
  }

  #pragma unroll
  for (int st = 0; st < 6; ++st) {
    int h = 32 >> st;
    int j = l & (h - 1);
    float sn, cs; __sincosf(-3.14159265358979f * (float)j / (float)h, &sn, &cs);
    float2 w = make_float2(cs, sn);
    bool hi = (l & h) != 0;
    #pragma unroll
    for (int m = 0; m < 12; ++m) {
      float px = __shfl_xor(y[m].x, h, 64);
      float py = __shfl_xor(y[m].y, h, 64);
      float2 p = make_float2(px, py);
      float2 lo  = cadd(y[m], p);
      float2 hiv = cmul(csub(p, y[m]), w);
      y[m] = hi ? hiv : lo;
    }
  }

  int r = ((l&1)<<5)|((l&2)<<3)|((l&4)<<1)|((l&8)>>1)|((l&16)>>3)|((l&32)>>5);
  float* Tb = T[grp];
  #pragma unroll
  for (int km = 0; km < 12; ++km) Tb[km*69 + r] = y[km].x;
  __syncthreads();

  #pragma unroll
  for (int mp = 0; mp < 12; ++mp) {
    int k = (mp << 6) + l;
    float v = Tb[(k % 12)*69 + (k / 12)];
    pre[k] = v;
    if (!special) pim[(N2 - k) % N2] = v;
  }
}

extern "C" void kernel_launch(void* const* d_in, const int* in_sizes, int n_in,
                              void* d_out, int out_size, void* d_ws, size_t ws_size,
                              hipStream_t stream) {
  const float* x = (const float*)d_in[0];
  float* out = (float*)d_out;
  if (ws_size >= WS_NEEDED) {
    float2* ws = (float2*)d_ws;
    p1a_kernel<<<dim3(1536), dim3(1024), 0, stream>>>(x, ws);
    p1b_kernel<<<dim3(1536), dim3(1024), 0, stream>>>(ws, out);
  } else {
    (void)hipFuncSetAttribute(reinterpret_cast<const void*>(&fft_seq_fused),
                              hipFuncAttributeMaxDynamicSharedMemorySize,
                              4 * CPBUF * (int)sizeof(float2));
    fft_seq_fused<<<dim3(768), dim3(1024), 4 * CPBUF * sizeof(float2), stream>>>(x, out);
  }
  fft_hid_kernel<<<dim3(4098), dim3(256), 0, stream>>>(out);
}

// Round 8
// 94.329 us; speedup vs baseline: 1.1762x; 1.1762x over previous
//
#include <hip/hip_runtime.h>
#include <hip/hip_bf16.h>

#define N1 4096
#define N2 768
#define NCC 384
#define WS_NEEDED 100663296ull     // ws1 (50.3 MB bf16) + ws2 (50.3 MB bf16)
#define WS1_UINTS 12582912ull      // 8*64*3*8192

__device__ __forceinline__ float2 cadd(float2 a, float2 b){ return make_float2(a.x+b.x, a.y+b.y); }
__device__ __forceinline__ float2 csub(float2 a, float2 b){ return make_float2(a.x-b.x, a.y-b.y); }
__device__ __forceinline__ float2 cmul(float2 a, float2 b){ return make_float2(a.x*b.x - a.y*b.y, a.x*b.y + a.y*b.x); }
__device__ __forceinline__ float2 cnegi(float2 a){ return make_float2(a.y, -a.x); }  // -i * a

// bf16x2 pack/unpack (RTN)
__device__ __forceinline__ unsigned pack_bf2(float2 v) {
  unsigned ax = __float_as_uint(v.x); ax = (ax + 0x7FFFu + ((ax >> 16) & 1u)) >> 16;
  unsigned ay = __float_as_uint(v.y); ay = (ay + 0x7FFFu + ((ay >> 16) & 1u)) & 0xFFFF0000u;
  return ax | ay;
}
__device__ __forceinline__ float2 unpack_bf2(unsigned u) {
  return make_float2(__uint_as_float(u << 16), __uint_as_float(u & 0xFFFF0000u));
}
__device__ __forceinline__ float bf2f(unsigned short u) {
  return __uint_as_float((unsigned)u << 16);
}

__device__ __forceinline__ int rev6(int p) {
  int k = 0;
  #pragma unroll
  for (int i = 0; i < 6; ++i) { k = (k << 2) | (p & 3); p >>= 2; }
  return k;
}

// In-register DIF FFT-8, natural-order outputs.
__device__ __forceinline__ void fft8(float2 z[8]) {
  const float RH = 0.70710678118654752f;
  float2 u0=cadd(z[0],z[4]), v0=csub(z[0],z[4]);
  float2 u1=cadd(z[1],z[5]), v1=csub(z[1],z[5]);
  float2 u2=cadd(z[2],z[6]), v2=csub(z[2],z[6]);
  float2 u3=cadd(z[3],z[7]), v3=csub(z[3],z[7]);
  v1 = make_float2(RH*(v1.x+v1.y), RH*(v1.y-v1.x));
  v2 = cnegi(v2);
  v3 = make_float2(RH*(v3.y-v3.x), -RH*(v3.x+v3.y));
  float2 a0=cadd(u0,u2), b0=csub(u0,u2);
  float2 a1=cadd(u1,u3), b1=cnegi(csub(u1,u3));
  float2 c0=cadd(v0,v2), d0=csub(v0,v2);
  float2 c1=cadd(v1,v3), d1=cnegi(csub(v1,v3));
  z[0]=cadd(a0,a1); z[4]=csub(a0,a1);
  z[2]=cadd(b0,b1); z[6]=csub(b0,b1);
  z[1]=cadd(c0,c1); z[5]=csub(c0,c1);
  z[3]=cadd(d0,d1); z[7]=csub(d0,d1);
}

// P1a: FFT-64 over b (rows a+64b), * W4096^{a*kb}, 128 complex cols per block.
// ws1 layout: [((b8*64+a)*3+cg)*8192 + kb*128 + c]  (uint bf16x2)
// -> each block writes ONE contiguous 32 KB region (streaming).
__global__ __launch_bounds__(1024) void p1a_kernel(const float* __restrict__ x,
                                                   unsigned* __restrict__ ws1) {
  __shared__ float4 S4[64*65];
  float2* S = reinterpret_cast<float2*>(S4);
  int bid = blockIdx.x;                          // 1536 = 8 * 192
  int b8  = bid & 7;
  int rem = bid >> 3;
  int cg  = rem / 64;                            // 0..2
  int a   = rem % 64;
  const int t = threadIdx.x, l = t & 63, w = t >> 6;

  const float* src = x + (size_t)b8 * N1 * N2 + (size_t)cg * 256;
  #pragma unroll
  for (int j = 0; j < 4; ++j) {
    int r   = 4*w + j;
    int row = a + 64*r;
    S4[r*65 + l] = *reinterpret_cast<const float4*>(src + (size_t)row * N2 + 4*l);
  }
  __syncthreads();

  const int c = t & 127, b0 = t >> 7;
  float2 z[8];
  #pragma unroll
  for (int b1 = 0; b1 < 8; ++b1) z[b1] = S[(8*b1 + b0)*130 + c];
  fft8(z);
  {
    float sn, cs; __sincosf(-6.283185307179586f/64.f * (float)b0, &sn, &cs);
    float2 wstep = make_float2(cs, sn), wcur = wstep;
    #pragma unroll
    for (int j = 1; j < 8; ++j) { z[j] = cmul(z[j], wcur); wcur = cmul(wcur, wstep); }
  }
  __syncthreads();
  #pragma unroll
  for (int j = 0; j < 8; ++j) S[(j*8 + b0)*130 + c] = z[j];
  __syncthreads();

  const int jj = t >> 7;
  #pragma unroll
  for (int b0i = 0; b0i < 8; ++b0i) z[b0i] = S[(jj*8 + b0i)*130 + c];
  fft8(z);                                       // z[m] = FFT64 at kb = 8m+jj
  float2 wc, w8;
  { float sn, cs; __sincosf(-6.283185307179586f/4096.f * (float)(a*jj), &sn, &cs); wc = make_float2(cs, sn); }
  { float sn, cs; __sincosf(-6.283185307179586f/4096.f * (float)(8*a),  &sn, &cs); w8 = make_float2(cs, sn); }
  unsigned* wdst = ws1 + (((size_t)b8*64 + a)*3 + cg)*8192 + (size_t)jj*128 + c;
  #pragma unroll
  for (int m = 0; m < 8; ++m) {
    wdst[(size_t)m * 1024] = pack_bf2(cmul(z[m], wc));
    wc = cmul(wc, w8);
  }
}

// P1b: FFT-64 over a for kb-pair {kb,64-kb}; Hermitian unpack; write packed
// plane ws2 (bf16): uint idx = (b8*4096 + r)*384 + col.
__global__ __launch_bounds__(1024) void p1b_kernel(const unsigned* __restrict__ ws1,
                                                   unsigned* __restrict__ ws2) {
  __shared__ float2 T[2][4096];
  int bid = blockIdx.x;                          // 1536 = 8*192
  int b8  = bid & 7;
  int rem = bid >> 3;
  int cg  = rem / 32, kbt = rem % 32;            // cg: 64-complex col group 0..5
  int kb0 = (kbt == 0) ? 0  : kbt;
  int kb1 = (kbt == 0) ? 32 : 64 - kbt;
  const int t = threadIdx.x, l = t & 63, wv = (t >> 6) & 7, ti = t >> 9;
  const int kb = ti ? kb1 : kb0;
  const int cgA = cg >> 1, chalf = (cg & 1) * 64;

  const unsigned* wsrc = ws1 + ((size_t)b8*64*3 + cgA)*8192
                             + (size_t)kb*128 + chalf + l;
  float2 z[8];
  #pragma unroll
  for (int a1 = 0; a1 < 8; ++a1)
    z[a1] = unpack_bf2(wsrc[(size_t)(8*a1 + wv) * 24576]);   // a*3*8192
  fft8(z);
  float fac = -6.283185307179586f/64.0f * (float)wv;
  #pragma unroll
  for (int q = 1; q < 8; ++q) {
    float sn, cs; __sincosf(fac * (float)q, &sn, &cs);
    z[q] = cmul(z[q], make_float2(cs, sn));
  }
  #pragma unroll
  for (int q = 0; q < 8; ++q) T[ti][(q*8 + wv)*64 + l] = z[q];
  __syncthreads();
  #pragma unroll
  for (int a0 = 0; a0 < 8; ++a0) z[a0] = T[ti][(wv*8 + a0)*64 + l];
  fft8(z);
  __syncthreads();
  #pragma unroll
  for (int ka1 = 0; ka1 < 8; ++ka1) T[ti][(8*ka1 + wv)*64 + l] = z[ka1];
  __syncthreads();

  unsigned* wout = ws2 + (size_t)b8 * N1 * NCC + (size_t)cg*64 + l;
  #pragma unroll
  for (int it = 0; it < 8; ++it) {
    int ka = 8*it + wv;
    int tj, kap;
    if (kbt == 0) { tj = ti; kap = ti ? (63 - ka) : ((64 - ka) & 63); }
    else          { tj = 1 - ti; kap = 63 - ka; }
    float2 Zk = T[ti][ka*64 + l];
    float2 Zp = T[tj][kap*64 + l];
    int r = kb + 64*ka;
    float2 o;
    if (r <= 2048) o = make_float2(0.5f*(Zk.x + Zp.x), 0.5f*(Zk.y + Zp.y));
    else           o = make_float2(0.5f*(Zp.y - Zk.y), 0.5f*(Zk.x - Zp.x));
    wout[(size_t)r * NCC] = pack_bf2(o);
  }
}

// Pass 2: FFT-768 per conjugate row pair, bf16 input plane, f32 out.
__global__ __launch_bounds__(256) void fft_hid_bf16(const unsigned* __restrict__ ws2,
                                                    float* __restrict__ out) {
  __shared__ float T[4][12*69];
  const int grp = threadIdx.x >> 6;
  const int l   = threadIdx.x & 63;
  int task = blockIdx.x * 4 + grp;              // 16392 = 4098*4
  int b  = task / 2049;
  int t1 = task - b * 2049;
  const bool special = (t1 == 0) || (t1 == 2048);
  const int mrow = special ? t1 : (N1 - t1);    // clamp: no OOB for specials
  const unsigned short* pre16 = (const unsigned short*)ws2 + ((size_t)b*N1 + t1)*N2;
  const unsigned short* pim16 = (const unsigned short*)ws2 + ((size_t)b*N1 + mrow)*N2;

  float2 z[12];
  #pragma unroll
  for (int m = 0; m < 12; ++m) {
    float re = bf2f(pre16[(m << 6) + l]);
    float im = special ? 0.0f : bf2f(pim16[(m << 6) + l]);
    z[m] = make_float2(re, im);
  }

  float2 A[3][4];
  #pragma unroll
  for (int q = 0; q < 3; ++q) {
    float2 s0 = z[q], s1 = z[3+q], s2 = z[6+q], s3 = z[9+q];
    float2 t0 = cadd(s0,s2), t1v = csub(s0,s2);
    float2 t2 = cadd(s1,s3), t3 = cnegi(csub(s1,s3));
    A[q][0] = cadd(t0,t2); A[q][1] = cadd(t1v,t3);
    A[q][2] = csub(t0,t2); A[q][3] = csub(t1v,t3);
  }
  const float h3 = 0.8660254037844386f;
  const float2 W1[4] = { {1.f,0.f}, {h3,-0.5f}, {0.5f,-h3}, {0.f,-1.f} };
  const float2 W2[4] = { {1.f,0.f}, {0.5f,-h3}, {-0.5f,-h3}, {-1.f,0.f} };
  float2 y[12];
  #pragma unroll
  for (int k4 = 0; k4 < 4; ++k4) {
    float2 C0 = A[0][k4];
    float2 C1 = cmul(A[1][k4], W1[k4]);
    float2 C2 = cmul(A[2][k4], W2[k4]);
    float2 tt = cadd(C1,C2), d = csub(C1,C2);
    float2 u  = make_float2(C0.x - 0.5f*tt.x, C0.y - 0.5f*tt.y);
    float2 idd = make_float2(h3*d.y, -h3*d.x);
    y[k4]   = cadd(C0, tt);
    y[k4+4] = cadd(u, idd);
    y[k4+8] = csub(u, idd);
  }

  float base = -6.283185307179586f * (float)l / 768.0f;
  #pragma unroll
  for (int km = 1; km < 12; ++km) {
    float sn, cs; __sincosf(base * (float)km, &sn, &cs);
    y[km] = cmul(y[km], make_float2(cs, sn));
  }

  #pragma unroll
  for (int st = 0; st < 6; ++st) {
    int h = 32 >> st;
    int j = l & (h - 1);
    float sn, cs; __sincosf(-3.14159265358979f * (float)j / (float)h, &sn, &cs);
    float2 w = make_float2(cs, sn);
    bool hi = (l & h) != 0;
    #pragma unroll
    for (int m = 0; m < 12; ++m) {
      float px = __shfl_xor(y[m].x, h, 64);
      float py = __shfl_xor(y[m].y, h, 64);
      float2 p = make_float2(px, py);
      float2 lo  = cadd(y[m], p);
      float2 hiv = cmul(csub(p, y[m]), w);
      y[m] = hi ? hiv : lo;
    }
  }

  int r = ((l&1)<<5)|((l&2)<<3)|((l&4)<<1)|((l&8)>>1)|((l&16)>>3)|((l&32)>>5);
  float* Tb = T[grp];
  #pragma unroll
  for (int km = 0; km < 12; ++km) Tb[km*69 + r] = y[km].x;
  __syncthreads();

  float* pre = out + ((size_t)b*N1 + t1)*N2;
  float* pim = out + ((size_t)b*N1 + mrow)*N2;
  #pragma unroll
  for (int mp = 0; mp < 12; ++mp) {
    int k = (mp << 6) + l;
    float v = Tb[(k % 12)*69 + (k / 12)];
    pre[k] = v;
    if (!special) pim[(N2 - k) % N2] = v;
  }
}

// ---------------- fallback path (no workspace): fused f32 pass 1 + f32 hid ----------------
#define PADI(i) ((i) + ((i) >> 4))
#define CPBUF 4352

__device__ __forceinline__ void bfly4p(float2* arr, int base, int M, float fac, int np) {
  float2 a0 = arr[PADI(base)], a1 = arr[PADI(base+M)];
  float2 a2 = arr[PADI(base+2*M)], a3 = arr[PADI(base+3*M)];
  float2 t0 = cadd(a0,a2), t1 = csub(a0,a2);
  float2 t2 = cadd(a1,a3), t3 = cnegi(csub(a1,a3));
  float2 y0 = cadd(t0,t2), y1 = cadd(t1,t3), y2 = csub(t0,t2), y3 = csub(t1,t3);
  float ang = fac * (float)np;
  float sn, cs; __sincosf(ang, &sn, &cs);
  float2 w1 = make_float2(cs, sn);
  float2 w2 = cmul(w1,w1);
  float2 w3 = cmul(w2,w1);
  arr[PADI(base)]     = y0;
  arr[PADI(base+M)]   = cmul(y1,w1);
  arr[PADI(base+2*M)] = cmul(y2,w2);
  arr[PADI(base+3*M)] = cmul(y3,w3);
}

__global__ __launch_bounds__(1024) void fft_seq_fused(const float* __restrict__ x,
                                                      float* __restrict__ out) {
  extern __shared__ float2 lds[];
  int bid = blockIdx.x;
  int wg  = (bid & 7) * 96 + (bid >> 3);
  int b   = wg / 96;
  int g   = wg % 96;
  const int t = threadIdx.x;
  const size_t base = (size_t)b * N1 * N2 + 8 * (size_t)g;

  for (int r = t; r < N1; r += 1024) {
    const float* p = x + base + (size_t)r * N2;
    float4 A  = *reinterpret_cast<const float4*>(p);
    float4 Bv = *reinterpret_cast<const float4*>(p + 4);
    int ip = PADI(r);
    lds[ip]             = make_float2(A.x, A.y);
    lds[CPBUF + ip]     = make_float2(A.z, A.w);
    lds[2*CPBUF + ip]   = make_float2(Bv.x, Bv.y);
    lds[3*CPBUF + ip]   = make_float2(Bv.z, Bv.w);
  }
  __syncthreads();

  const int wv  = t >> 6;
  const int cp  = wv & 3;
  const int idx = ((wv >> 2) << 6) + (t & 63);
  float2* buf = lds + cp * CPBUF;

  #pragma unroll
  for (int s = 0; s < 6; ++s) {
    int lm = 10 - 2*s;
    int M  = 1 << lm;
    float fac = -6.283185307179586f / (float)(4*M);
    #pragma unroll
    for (int jj = 0; jj < 4; ++jj) {
      int j   = idx + (jj << 8);
      int np  = j & (M-1);
      int grp = j >> lm;
      int bse = (grp << (lm+2)) + np;
      bfly4p(buf, bse, M, fac, np);
    }
    __syncthreads();
  }

  float* orow = out + base;
  #pragma unroll
  for (int i = 0; i < 4; ++i) {
    int k  = ((t & 63) << 6) + (t >> 6) + (i << 4);
    int km = (N1 - k) & (N1 - 1);
    int pk = PADI(rev6(k));
    int pn = PADI(rev6(km));
    float o[8];
    #pragma unroll
    for (int c = 0; c < 4; ++c) {
      float2 zk = lds[c*CPBUF + pk];
      float2 zn = lds[c*CPBUF + pn];
      if (k <= 2048) { o[2*c] = 0.5f*(zk.x + zn.x); o[2*c+1] = 0.5f*(zk.y + zn.y); }
      else           { o[2*c] = 0.5f*(zn.y - zk.y); o[2*c+1] = 0.5f*(zk.x - zn.x); }
    }
    float* q = orow + (size_t)k * N2;
    *reinterpret_cast<float4*>(q)     = make_float4(o[0], o[1], o[2], o[3]);
    *reinterpret_cast<float4*>(q + 4) = make_float4(o[4], o[5], o[6], o[7]);
  }
}

__global__ __launch_bounds__(256) void fft_hid_f32(float* __restrict__ out) {
  __shared__ float T[4][12*69];
  const int grp = threadIdx.x >> 6;
  const int l   = threadIdx.x & 63;
  int task = blockIdx.x * 4 + grp;
  int b  = task / 2049;
  int t1 = task - b * 2049;
  const bool special = (t1 == 0) || (t1 == 2048);
  const int mrow = special ? t1 : (N1 - t1);
  float* baseB = out + (size_t)b * N1 * N2;
  float* pre = baseB + (size_t)t1 * N2;
  float* pim = baseB + (size_t)mrow * N2;

  float2 z[12];
  #pragma unroll
  for (int m = 0; m < 12; ++m) {
    float re = pre[(m << 6) + l];
    float im = special ? 0.0f : pim[(m << 6) + l];
    z[m] = make_float2(re, im);
  }

  float2 A[3][4];
  #pragma unroll
  for (int q = 0; q < 3; ++q) {
    float2 s0 = z[q], s1 = z[3+q], s2 = z[6+q], s3 = z[9+q];
    float2 t0 = cadd(s0,s2), t1v = csub(s0,s2);
    float2 t2 = cadd(s1,s3), t3 = cnegi(csub(s1,s3));
    A[q][0] = cadd(t0,t2); A[q][1] = cadd(t1v,t3);
    A[q][2] = csub(t0,t2); A[q][3] = csub(t1v,t3);
  }
  const float h3 = 0.8660254037844386f;
  const float2 W1[4] = { {1.f,0.f}, {h3,-0.5f}, {0.5f,-h3}, {0.f,-1.f} };
  const float2 W2[4] = { {1.f,0.f}, {0.5f,-h3}, {-0.5f,-h3}, {-1.f,0.f} };
  float2 y[12];
  #pragma unroll
  for (int k4 = 0; k4 < 4; ++k4) {
    float2 C0 = A[0][k4];
    float2 C1 = cmul(A[1][k4], W1[k4]);
    float2 C2 = cmul(A[2][k4], W2[k4]);
    float2 tt = cadd(C1,C2), d = csub(C1,C2);
    float2 u  = make_float2(C0.x - 0.5f*tt.x, C0.y - 0.5f*tt.y);
    float2 idd = make_float2(h3*d.y, -h3*d.x);
    y[k4]   = cadd(C0, tt);
    y[k4+4] = cadd(u, idd);
    y[k4+8] = csub(u, idd);
  }

  float base = -6.283185307179586f * (float)l / 768.0f;
  #pragma unroll
  for (int km = 1; km < 12; ++km) {
    float sn, cs; __sincosf(base * (float)km, &sn, &cs);
    y[km] = cmul(y[km], make_float2(cs, sn));
  }

  #pragma unroll
  for (int st = 0; st < 6; ++st) {
    int h = 32 >> st;
    int j = l & (h - 1);
    float sn, cs; __sincosf(-3.14159265358979f * (float)j / (float)h, &sn, &cs);
    float2 w = make_float2(cs, sn);
    bool hi = (l & h) != 0;
    #pragma unroll
    for (int m = 0; m < 12; ++m) {
      float px = __shfl_xor(y[m].x, h, 64);
      float py = __shfl_xor(y[m].y, h, 64);
      float2 p = make_float2(px, py);
      float2 lo  = cadd(y[m], p);
      float2 hiv = cmul(csub(p, y[m]), w);
      y[m] = hi ? hiv : lo;
    }
  }

  int r = ((l&1)<<5)|((l&2)<<3)|((l&4)<<1)|((l&8)>>1)|((l&16)>>3)|((l&32)>>5);
  float* Tb = T[grp];
  #pragma unroll
  for (int km = 0; km < 12; ++km) Tb[km*69 + r] = y[km].x;
  __syncthreads();

  #pragma unroll
  for (int mp = 0; mp < 12; ++mp) {
    int k = (mp << 6) + l;
    float v = Tb[(k % 12)*69 + (k / 12)];
    pre[k] = v;
    if (!special) pim[(N2 - k) % N2] = v;
  }
}

extern "C" void kernel_launch(void* const* d_in, const int* in_sizes, int n_in,
                              void* d_out, int out_size, void* d_ws, size_t ws_size,
                              hipStream_t stream) {
  const float* x = (const float*)d_in[0];
  float* out = (float*)d_out;
  if (ws_size >= WS_NEEDED) {
    unsigned* ws1 = (unsigned*)d_ws;
    unsigned* ws2 = ws1 + WS1_UINTS;
    p1a_kernel<<<dim3(1536), dim3(1024), 0, stream>>>(x, ws1);
    p1b_kernel<<<dim3(1536), dim3(1024), 0, stream>>>(ws1, ws2);
    fft_hid_bf16<<<dim3(4098), dim3(256), 0, stream>>>(ws2, out);
  } else {
    (void)hipFuncSetAttribute(reinterpret_cast<const void*>(&fft_seq_fused),
                              hipFuncAttributeMaxDynamicSharedMemorySize,
                              4 * CPBUF * (int)sizeof(float2));
    fft_seq_fused<<<dim3(768), dim3(1024), 4 * CPBUF * sizeof(float2), stream>>>(x, out);
    fft_hid_f32<<<dim3(4098), dim3(256), 0, stream>>>(out);
  }
}